// Round 28
// baseline (75.481 us; speedup 1.0000x reference)
//
#include <hip/hip_runtime.h>
#include <stdint.h>

#define KK 5
#define SCALE_F 50000.0f
#define OC 128
#define IC 128
#define HH 56
#define WW 56
#define NB 64
#define HWSZ (HH * WW)          // 3136
#define NTAP 9
#define NWEL (OC * IC * NTAP)   // 147456

// ---- MFMA path geometry ----
#define PD 58                   // padded spatial dim
#define NICQ 8                  // 16-byte ic-chunks per pixel (128 ic)
// apk8 chunk index: ((n*PD + hh)*NICQ + icq)*PD + ww ; byte addr = chunk*16
// bfrag chunk index: (kk*4 + oct)*64 + lane   (kk = icb*9 + tap)

// ---- bitplane fallback geometry (verified R5) ----
#define PW 60
#define PROWS 58
#define PLANE (PROWS * PW)      // 3480
#define PLSTRIDE (NB * PLANE)   // 222720
#define OCPB 2
#define WPT 4

typedef int v4i  __attribute__((ext_vector_type(4)));
typedef int v16i __attribute__((ext_vector_type(16)));

__device__ __forceinline__ constexpr int koff2(int kk) {
    int icb = kk / 9, tap = kk % 9;
    int dh = tap / 3 - 1, dw = tap % 3 - 1;
    return (dh * NICQ + icb * 2) * PD + dw;
}

// ===========================================================================
// ============================ MFMA (primary) path ==========================
// ===========================================================================

// Kernel 1: FULLY FUSED prep — one launch does all of:
//   blocks [0,896):     apack  (binarize x -> int8 chunked layout)
//   blocks [896,1226):  wpack  (SDP weight gen -> MFMA B-fragment order)
//   blocks [1226,1487): border (zero apk8 padded borders)
__global__ void __launch_bounds__(448) prep_kernel(
    const float* __restrict__ x, const float* __restrict__ M,
    const float* __restrict__ Z, const float* __restrict__ rv,
    int8_t* __restrict__ bfrag, int8_t* __restrict__ apk8) {
    int tx = threadIdx.x;
    int bx = blockIdx.x;

    if (bx < 896) {
        // ---- apack (vectorized, G13): 16 aligned float4 loads/thread ----
        int local = tx % 112, hloc = tx / 112;
        int sw  = local % 14;
        int icq = local / 14;
        int h = (bx % 14) * 4 + hloc;     // 0..55
        int n = bx / 14;                  // 0..63
        int w0 = sw * 4;
        const float* xp = x + ((size_t)n * IC + icq * 16) * HWSZ + h * WW + w0;

        uint32_t pk0[4] = {0,0,0,0}, pk1[4] = {0,0,0,0},
                 pk2[4] = {0,0,0,0}, pk3[4] = {0,0,0,0};
#pragma unroll
        for (int c = 0; c < 16; ++c) {
            float4 v = *(const float4*)(xp + (size_t)c * HWSZ);
            int wd = c >> 2, sh = (c & 3) * 8;
            pk0[wd] |= ((v.x > 0.0f) ? 0x01u : 0xFFu) << sh;
            pk1[wd] |= ((v.y > 0.0f) ? 0x01u : 0xFFu) << sh;
            pk2[wd] |= ((v.z > 0.0f) ? 0x01u : 0xFFu) << sh;
            pk3[wd] |= ((v.w > 0.0f) ? 0x01u : 0xFFu) << sh;
        }
        size_t chunk0 = (((size_t)n * PD + (h + 1)) * NICQ + icq) * PD + (w0 + 1);
        *(uint4*)(apk8 + (chunk0 + 0) * 16) = make_uint4(pk0[0], pk0[1], pk0[2], pk0[3]);
        *(uint4*)(apk8 + (chunk0 + 1) * 16) = make_uint4(pk1[0], pk1[1], pk1[2], pk1[3]);
        *(uint4*)(apk8 + (chunk0 + 2) * 16) = make_uint4(pk2[0], pk2[1], pk2[2], pk2[3]);
        *(uint4*)(apk8 + (chunk0 + 3) * 16) = make_uint4(pk3[0], pk3[1], pk3[2], pk3[3]);
    } else if (bx < 1226) {
        // ---- wpack ----
        int i = (bx - 896) * 448 + tx;
        if (i < NWEL) {
            int oc = i / 1152;
            int r1 = i - oc * 1152;
            int ic = r1 / 9;
            int tap = r1 - ic * 9;

            float m  = M[i];
            float z0 = Z[0 * NWEL + i];
            float z1 = Z[1 * NWEL + i];
            float z2 = Z[2 * NWEL + i];
            float z3 = Z[3 * NWEL + i];
            float z4 = Z[4 * NWEL + i];
            float s  = z0 * z0 + z1 * z1 + z2 * z2 + z3 * z3 + z4 * z4;
            float A  = m * m + s * (1.0f / SCALE_F);
            float inv = 1.0f / sqrtf(A);
            float w = rv[0] * (z0 * inv);
            w += rv[1] * (z1 * inv);
            w += rv[2] * (z2 * inv);
            w += rv[3] * (z3 * inv);
            w += rv[4] * (z4 * inv);
            w += m * inv;

            int8_t sv = (w > 0.0f) ? (int8_t)1 : (int8_t)-1;
            int icb = ic >> 5, khalf = (ic >> 4) & 1, b = ic & 15;
            int kk  = icb * 9 + tap;              // K order matches bconv
            int oct = oc >> 5;
            int lane = khalf * 32 + (oc & 31);
            bfrag[(size_t)((kk * 4 + oct) * 64 + lane) * 16 + b] = sv;
        }
    } else {
        // ---- border zeroing ----
        int j = (bx - 1226) * 448 + tx;
        if (j < NB * 1824) {
            int n  = j / 1824;
            int rj = j - n * 1824;
            int hh, icq, ww;
            if (rj < 928) {                        // rows 0 and 57
                hh = (rj / 464) * 57;
                int q = rj % 464;
                icq = q / PD;
                ww  = q - icq * PD;
            } else {                               // cols 0 and 57, rows 1..56
                int q = rj - 928;                  // < 896
                hh = 1 + (q >> 4);
                int r2 = q & 15;
                icq = r2 >> 1;
                ww  = (r2 & 1) * 57;
            }
            size_t chunk = (((size_t)n * PD + hh) * NICQ + icq) * PD + ww;
            *(int4*)(apk8 + chunk * 16) = make_int4(0, 0, 0, 0);
        }
    }
}

// A-load via inline asm: INVISIBLE to the compiler's waitcnt tracker, so the
// only vmcnt waits in the K-loop are OUR counted ones (AITER pattern, T4).
#define ALOAD(slot, kkp)                                                     \
    asm volatile("global_load_dwordx4 %0, %1, off"                           \
                 : "=v"(ar[slot])                                            \
                 : "v"((uint64_t)(uintptr_t)(apk8 + ((size_t)(ab0 + koff2(kkp)) << 4))))

// Kernel 2: implicit-GEMM conv — R27 inner loop, 16-WAVE BLOCKS.
// grid = 784 (392 px-blocks x 2 oc-halves, exact), block = 1024 thr = 16
// waves sharing ONE 72 KB B-half in LDS. Same LDS footprint as the 8-wave
// variant but 4 waves/SIMD at 1 block/CU — double the wave concurrency at
// zero extra traffic/barriers (the never-tested occupancy cell). Wave =
// 32 px x 64 oc; counted asm vmcnt (steady 6-deep); zero K-loop barriers;
// T5 setprio around the MFMA pair. ~112 VGPR, lb(1024,4).
__global__ void __launch_bounds__(1024, 4) bconv_kernel(
    const int8_t* __restrict__ apk8, const int8_t* __restrict__ bfrag,
    const float* __restrict__ alpha, float* __restrict__ out) {
    __shared__ uint4 ldsB[4608];   // [kk36][j2][lane64], 73,728 B

    int tx = threadIdx.x;
    int lane = tx & 63, wid = tx >> 6;        // wid 0..15
    int half = lane >> 5, l31 = lane & 31;

    // bijective XCD swizzle (784 = 8 * 98); och pairs colocate per XCD
    int bid = blockIdx.x;
    int swz = (bid & 7) * 98 + (bid >> 3);     // 0..783
    int och = swz & 1;
    int pxb = swz >> 1;                        // 0..391
    int ocb = och * 64;

    int px = pxb * 512 + wid * 32 + l31;       // < 200704 exactly
    int n  = px / HWSZ;
    int hw = px - n * HWSZ;
    int h  = hw / WW;
    int w  = hw - h * WW;
    int ab0 = ((n * PD + h + 1) * NICQ + half) * PD + (w + 1);
    size_t ob0 = ((size_t)n * OC + ocb + half) * HWSZ + hw;

    // ---- A ring-8: issue 7 asm loads BEFORE B staging (latency overlap) ----
    v4i ar[8];
    ALOAD(0, 0); ALOAD(1, 1); ALOAD(2, 2); ALOAD(3, 3);
    ALOAD(4, 4); ALOAD(5, 5); ALOAD(6, 6);

    // ---- stage B-half via global_load_lds (direct DMA, width=16) ----
    // rows 0..71 = kk*2+j; 16 waves x 5 strided passes (guarded).
    const uint4* gB = (const uint4*)bfrag;
#pragma unroll
    for (int s = 0; s < 5; ++s) {
        int row = wid + s * 16;
        if (row < 72) {
            int kk = row >> 1, j = row & 1;
            const uint4* src = &gB[((kk << 2) + (och << 1) + j) * 64 + lane];
            __builtin_amdgcn_global_load_lds(
                (const uint32_t*)src,
                (uint32_t*)&ldsB[row * 64 + lane], 16, 0, 0);
        }
    }
    __syncthreads();   // compiler drains vmcnt(0): staging DMA + our A loads

    // ---- B ring-4: preload kk = 0..2 ----
    v4i b0r[4], b1r[4];
#pragma unroll
    for (int i = 0; i < 3; ++i) {
        b0r[i] = *(const v4i*)&ldsB[i * 128 + lane];
        b1r[i] = *(const v4i*)&ldsB[i * 128 + 64 + lane];
    }

    v16i acc0 = {}, acc1 = {};
#pragma unroll
    for (int kk = 0; kk < 36; ++kk) {
        // counted wait: ensure load idx kk landed; keep up to 6 newer in flight
        if (kk <= 29)      asm volatile("s_waitcnt vmcnt(6)");
        else if (kk == 30) asm volatile("s_waitcnt vmcnt(5)");
        else if (kk == 31) asm volatile("s_waitcnt vmcnt(4)");
        else if (kk == 32) asm volatile("s_waitcnt vmcnt(3)");
        else if (kk == 33) asm volatile("s_waitcnt vmcnt(2)");
        else if (kk == 34) asm volatile("s_waitcnt vmcnt(1)");
        else               asm volatile("s_waitcnt vmcnt(0)");
        __builtin_amdgcn_sched_barrier(0);   // rule #18: no MFMA above the wait

        if (kk + 7 < 36) ALOAD((kk + 7) & 7, kk + 7);   // issue 7 ahead

        if (kk + 3 < 36) {                   // B prefetch, 3 ahead (compiler lgkmcnt)
            b0r[(kk + 3) & 3] = *(const v4i*)&ldsB[(kk + 3) * 128 + lane];
            b1r[(kk + 3) & 3] = *(const v4i*)&ldsB[(kk + 3) * 128 + 64 + lane];
        }
        v4i A = ar[kk & 7];
        __builtin_amdgcn_s_setprio(1);       // T5: favor MFMA-issuing wave
        acc0 = __builtin_amdgcn_mfma_i32_32x32x32_i8(A, b0r[kk & 3], acc0, 0, 0, 0);
        acc1 = __builtin_amdgcn_mfma_i32_32x32x32_i8(A, b1r[kk & 3], acc1, 0, 0, 0);
        __builtin_amdgcn_s_setprio(0);
    }

    __syncthreads();   // ldsB free -> reuse as transpose scratch

    // ---- epilogue: alpha-scale + wave-private LDS transpose (validated) ----
    float* tlw = (float*)ldsB + wid * (32 * 33);   // 16 waves x 4224 B = 67.6 KB
    float alf0 = alpha[ocb + l31];
    float alf1 = alpha[ocb + 32 + l31];

#pragma unroll
    for (int tn = 0; tn < 2; ++tn) {
        const v16i* ac = tn ? &acc1 : &acc0;
        float alf = tn ? alf1 : alf0;
        // C layout: col(oc)=lane&31, row(px)=(r&3)+8*(r>>2)+4*half
#pragma unroll
        for (int r = 0; r < 16; ++r) {
            int row = (r & 3) + 8 * (r >> 2) + 4 * half;
            tlw[row * 33 + l31] = (float)(*ac)[r] * alf;
        }
        // wave-synchronous transpose read: lane -> (px=l31, oc=2r+half)
#pragma unroll
        for (int r = 0; r < 16; ++r) {
            float v = tlw[l31 * 33 + 2 * r + half];
            out[ob0 + (size_t)(tn * 32 + 2 * r) * HWSZ] = v;
        }
    }
}

// ===========================================================================
// ================== bitplane fallback path (verified R5) ===================
// ===========================================================================

__global__ void __launch_bounds__(256) wpack32_kernel(
    const float* __restrict__ M, const float* __restrict__ Z,
    const float* __restrict__ rv, uint32_t* __restrict__ wpk32) {
    int gtid = blockIdx.x * blockDim.x + threadIdx.x;
    int lane = gtid & 63;
    int wid  = gtid >> 6;
    int oc   = wid / 18;
    int r    = wid - oc * 18;
    int tap  = r >> 1;
    int word = r & 1;
    int ic   = word * 64 + lane;
    int idx  = (oc * IC + ic) * NTAP + tap;

    float m  = M[idx];
    float z0 = Z[0 * NWEL + idx];
    float z1 = Z[1 * NWEL + idx];
    float z2 = Z[2 * NWEL + idx];
    float z3 = Z[3 * NWEL + idx];
    float z4 = Z[4 * NWEL + idx];
    float s  = z0 * z0 + z1 * z1 + z2 * z2 + z3 * z3 + z4 * z4;
    float A  = m * m + s * (1.0f / SCALE_F);
    float inv = 1.0f / sqrtf(A);
    float w = rv[0] * (z0 * inv);
    w += rv[1] * (z1 * inv);
    w += rv[2] * (z2 * inv);
    w += rv[3] * (z3 * inv);
    w += rv[4] * (z4 * inv);
    w += m * inv;

    unsigned long long b = __ballot(w > 0.0f);
    if (lane == 0) {
        uint64_t* wpk = (uint64_t*)wpk32;
        wpk[(oc * NTAP + tap) * 2 + word] = b;
    }
}

__global__ void __launch_bounds__(256) apack32_kernel(
    const float* __restrict__ x, uint32_t* __restrict__ apk32) {
    int q  = blockIdx.x * blockDim.x + threadIdx.x;
    int wd = blockIdx.y;
    int n  = q / HWSZ;
    int hw = q - n * HWSZ;
    int h  = hw / WW;
    int w  = hw - h * WW;
    const float* xp = x + (size_t)n * IC * HWSZ + (size_t)wd * 32 * HWSZ + hw;

    uint32_t b = 0;
#pragma unroll
    for (int c = 0; c < 32; ++c)
        b |= (uint32_t)(xp[(size_t)c * HWSZ] > 0.0f) << c;

    apk32[(size_t)wd * PLSTRIDE + (size_t)n * PLANE + (size_t)(h + 1) * PW + (w + 1)] = b;
}

__global__ void __launch_bounds__(256, 8) bconv32_kernel(
    const uint32_t* __restrict__ apk32, const uint32_t* __restrict__ wpk32,
    const float* __restrict__ alpha, float* __restrict__ out) {
    __shared__ int adj[OCPB][9];
    __shared__ float alf[OCPB];

    int tx  = threadIdx.x;
    int oc0 = blockIdx.y * OCPB;

    if (tx < OCPB) alf[tx] = alpha[oc0 + tx];
    if (tx < OCPB * 9) {
        int ocl = tx / 9, cls = tx % 9;
        int rc = cls / 3, cc = cls % 3;
        int nv = ((rc == 1) ? 3 : 2) * ((cc == 1) ? 3 : 2);
        int s = 0;
#pragma unroll
        for (int t = 0; t < NTAP; ++t) {
            int i = t / 3, j = t % 3;
            bool invld = (rc == 0 && i == 0) || (rc == 2 && i == 2) ||
                         (cc == 0 && j == 0) || (cc == 2 && j == 2);
            if (invld) {
                const uint64_t* wpk = (const uint64_t*)wpk32;
                uint64_t lo = wpk[(oc0 + ocl) * NTAP * 2 + t * 2 + 0];
                uint64_t hi = wpk[(oc0 + ocl) * NTAP * 2 + t * 2 + 1];
                s += __popcll(lo) + __popcll(hi);
            }
        }
        adj[ocl][cls] = 128 * nv + 2 * s;
    }
    __syncthreads();

    int t  = blockIdx.x * blockDim.x + tx;
    int sw = t % 14;
    int h  = (t / 14) % HH;
    int n  = t / (14 * HH);
    int w0 = sw * WPT;

    const uint32_t* ap = apk32 + (size_t)n * PLANE + (size_t)h * PW + w0;
    const uint64_t* wpk = (const uint64_t*)wpk32;

    int cnt[WPT * OCPB] = {0};
#pragma unroll 1
    for (int r = 0; r < 3; ++r) {
#pragma unroll 1
        for (int wd = 0; wd < 4; ++wd) {
            const uint32_t* p = ap + (size_t)wd * PLSTRIDE + (size_t)r * PW;
            uint32_t T[6];
#pragma unroll
            for (int c = 0; c < 6; ++c) T[c] = p[c];
#pragma unroll
            for (int j = 0; j < 3; ++j) {
#pragma unroll
                for (int ocl = 0; ocl < OCPB; ++ocl) {
                    uint64_t w2 = wpk[(oc0 + ocl) * NTAP * 2 + (r * 3 + j) * 2 + (wd >> 1)];
                    uint32_t wv = (wd & 1) ? (uint32_t)(w2 >> 32) : (uint32_t)w2;
#pragma unroll
                    for (int o = 0; o < WPT; ++o)
                        cnt[o * OCPB + ocl] += __popc(T[j + o] ^ wv);
                }
            }
        }
    }

    int rcls = (h == 0) ? 0 : ((h == HH - 1) ? 6 : 3);
    int clsL = rcls + ((w0 == 0) ? 0 : 1);
    int clsI = rcls + 1;
    int clsR = rcls + ((w0 == WW - WPT) ? 2 : 1);
    float* op = out + ((size_t)n * OC + oc0) * HWSZ + h * WW + w0;
#pragma unroll
    for (int ocl = 0; ocl < OCPB; ++ocl) {
        float a = alf[ocl];
        float4 v;
        v.x = (float)(adj[ocl][clsL] - 2 * cnt[0 * OCPB + ocl]) * a;
        v.y = (float)(adj[ocl][clsI] - 2 * cnt[1 * OCPB + ocl]) * a;
        v.z = (float)(adj[ocl][clsI] - 2 * cnt[2 * OCPB + ocl]) * a;
        v.w = (float)(adj[ocl][clsR] - 2 * cnt[3 * OCPB + ocl]) * a;
        *(float4*)(op + (size_t)ocl * HWSZ) = v;
    }
}

extern "C" void kernel_launch(void* const* d_in, const int* in_sizes, int n_in,
                              void* d_out, int out_size, void* d_ws, size_t ws_size,
                              hipStream_t stream) {
    const float* x     = (const float*)d_in[0];
    const float* M     = (const float*)d_in[1];
    const float* Z     = (const float*)d_in[2];
    const float* Alpha = (const float*)d_in[3];
    const float* rv    = (const float*)d_in[4];
    float* out = (float*)d_out;

    const size_t mfma_needed = 196608 + (size_t)NB * PD * NICQ * PD * 16 + (1 << 20);

    if (ws_size >= mfma_needed) {
        int8_t* bfrag = (int8_t*)d_ws;                      // 147,456 B
        int8_t* apk8  = (int8_t*)d_ws + 196608;             // 27,557,888 B

        prep_kernel<<<1487, 448, 0, stream>>>(x, M, Z, rv, bfrag, apk8);
        bconv_kernel<<<784, 1024, 0, stream>>>(apk8, bfrag, Alpha, out);
    } else {
        // verified bitplane fallback (R5)
        uint32_t* wpk32 = (uint32_t*)d_ws;                  // 18,432 B
        uint32_t* apk32 = (uint32_t*)((char*)d_ws + 32768); // 3,563,520 B

        hipMemsetAsync(apk32, 0, (size_t)4 * PLSTRIDE * 4, stream);
        wpack32_kernel<<<NWEL / 256, 256, 0, stream>>>(M, Z, rv, wpk32);
        apack32_kernel<<<dim3((NB * HWSZ) / 256, 4), 256, 0, stream>>>(x, apk32);
        bconv32_kernel<<<dim3((NB * HH * 14) / 256, OC / OCPB), 256, 0, stream>>>(
            apk32, wpk32, Alpha, out);
    }
}

// Round 29
// 66.323 us; speedup vs baseline: 1.1381x; 1.1381x over previous
//
#include <hip/hip_runtime.h>
#include <stdint.h>

#define KK 5
#define SCALE_F 50000.0f
#define OC 128
#define IC 128
#define HH 56
#define WW 56
#define NB 64
#define HWSZ (HH * WW)          // 3136
#define NTAP 9
#define NWEL (OC * IC * NTAP)   // 147456

// ---- MFMA path geometry ----
#define PD 58                   // padded spatial dim
#define NICQ 8                  // 16-byte ic-chunks per pixel (128 ic)
// apk8 chunk index: ((n*PD + hh)*NICQ + icq)*PD + ww ; byte addr = chunk*16
// bfrag chunk index: (kk*4 + oct)*64 + lane   (kk = icb*9 + tap)

// ---- bitplane fallback geometry (verified R5) ----
#define PW 60
#define PROWS 58
#define PLANE (PROWS * PW)      // 3480
#define PLSTRIDE (NB * PLANE)   // 222720
#define OCPB 2
#define WPT 4

typedef int v4i  __attribute__((ext_vector_type(4)));
typedef int v16i __attribute__((ext_vector_type(16)));

__device__ __forceinline__ constexpr int koff2(int kk) {
    int icb = kk / 9, tap = kk % 9;
    int dh = tap / 3 - 1, dw = tap % 3 - 1;
    return (dh * NICQ + icb * 2) * PD + dw;
}

// ===========================================================================
// ============================ MFMA (primary) path ==========================
// ===========================================================================

// Kernel 1: FULLY FUSED prep — one launch does all of:
//   blocks [0,896):     apack  (binarize x -> int8 chunked layout)
//   blocks [896,1226):  wpack  (SDP weight gen -> MFMA B-fragment order)
//   blocks [1226,1487): border (zero apk8 padded borders)
__global__ void __launch_bounds__(448) prep_kernel(
    const float* __restrict__ x, const float* __restrict__ M,
    const float* __restrict__ Z, const float* __restrict__ rv,
    int8_t* __restrict__ bfrag, int8_t* __restrict__ apk8) {
    int tx = threadIdx.x;
    int bx = blockIdx.x;

    if (bx < 896) {
        // ---- apack (vectorized, G13): 16 aligned float4 loads/thread ----
        int local = tx % 112, hloc = tx / 112;
        int sw  = local % 14;
        int icq = local / 14;
        int h = (bx % 14) * 4 + hloc;     // 0..55
        int n = bx / 14;                  // 0..63
        int w0 = sw * 4;
        const float* xp = x + ((size_t)n * IC + icq * 16) * HWSZ + h * WW + w0;

        uint32_t pk0[4] = {0,0,0,0}, pk1[4] = {0,0,0,0},
                 pk2[4] = {0,0,0,0}, pk3[4] = {0,0,0,0};
#pragma unroll
        for (int c = 0; c < 16; ++c) {
            float4 v = *(const float4*)(xp + (size_t)c * HWSZ);
            int wd = c >> 2, sh = (c & 3) * 8;
            pk0[wd] |= ((v.x > 0.0f) ? 0x01u : 0xFFu) << sh;
            pk1[wd] |= ((v.y > 0.0f) ? 0x01u : 0xFFu) << sh;
            pk2[wd] |= ((v.z > 0.0f) ? 0x01u : 0xFFu) << sh;
            pk3[wd] |= ((v.w > 0.0f) ? 0x01u : 0xFFu) << sh;
        }
        size_t chunk0 = (((size_t)n * PD + (h + 1)) * NICQ + icq) * PD + (w0 + 1);
        *(uint4*)(apk8 + (chunk0 + 0) * 16) = make_uint4(pk0[0], pk0[1], pk0[2], pk0[3]);
        *(uint4*)(apk8 + (chunk0 + 1) * 16) = make_uint4(pk1[0], pk1[1], pk1[2], pk1[3]);
        *(uint4*)(apk8 + (chunk0 + 2) * 16) = make_uint4(pk2[0], pk2[1], pk2[2], pk2[3]);
        *(uint4*)(apk8 + (chunk0 + 3) * 16) = make_uint4(pk3[0], pk3[1], pk3[2], pk3[3]);
    } else if (bx < 1226) {
        // ---- wpack ----
        int i = (bx - 896) * 448 + tx;
        if (i < NWEL) {
            int oc = i / 1152;
            int r1 = i - oc * 1152;
            int ic = r1 / 9;
            int tap = r1 - ic * 9;

            float m  = M[i];
            float z0 = Z[0 * NWEL + i];
            float z1 = Z[1 * NWEL + i];
            float z2 = Z[2 * NWEL + i];
            float z3 = Z[3 * NWEL + i];
            float z4 = Z[4 * NWEL + i];
            float s  = z0 * z0 + z1 * z1 + z2 * z2 + z3 * z3 + z4 * z4;
            float A  = m * m + s * (1.0f / SCALE_F);
            float inv = 1.0f / sqrtf(A);
            float w = rv[0] * (z0 * inv);
            w += rv[1] * (z1 * inv);
            w += rv[2] * (z2 * inv);
            w += rv[3] * (z3 * inv);
            w += rv[4] * (z4 * inv);
            w += m * inv;

            int8_t sv = (w > 0.0f) ? (int8_t)1 : (int8_t)-1;
            int icb = ic >> 5, khalf = (ic >> 4) & 1, b = ic & 15;
            int kk  = icb * 9 + tap;              // K order matches bconv
            int oct = oc >> 5;
            int lane = khalf * 32 + (oc & 31);
            bfrag[(size_t)((kk * 4 + oct) * 64 + lane) * 16 + b] = sv;
        }
    } else {
        // ---- border zeroing ----
        int j = (bx - 1226) * 448 + tx;
        if (j < NB * 1824) {
            int n  = j / 1824;
            int rj = j - n * 1824;
            int hh, icq, ww;
            if (rj < 928) {                        // rows 0 and 57
                hh = (rj / 464) * 57;
                int q = rj % 464;
                icq = q / PD;
                ww  = q - icq * PD;
            } else {                               // cols 0 and 57, rows 1..56
                int q = rj - 928;                  // < 896
                hh = 1 + (q >> 4);
                int r2 = q & 15;
                icq = r2 >> 1;
                ww  = (r2 & 1) * 57;
            }
            size_t chunk = (((size_t)n * PD + hh) * NICQ + icq) * PD + ww;
            *(int4*)(apk8 + chunk * 16) = make_int4(0, 0, 0, 0);
        }
    }
}

// A-load via inline asm: INVISIBLE to the compiler's waitcnt tracker, so the
// only vmcnt waits in the K-loop are OUR counted ones (AITER pattern, T4).
#define ALOAD(slot, kkp)                                                     \
    asm volatile("global_load_dwordx4 %0, %1, off"                           \
                 : "=v"(ar[slot])                                            \
                 : "v"((uint64_t)(uintptr_t)(apk8 + ((size_t)(ab0 + koff2(kkp)) << 4))))

// Kernel 2: implicit-GEMM conv — R27 best configuration (validated).
// grid = 1568, 512 thr = 8 waves, wave = 32 px x 64 oc, B-half 72 KB LDS
// staged via global_load_lds DMA, counted asm vmcnt (steady 6-deep),
// zero K-loop barriers, T5 setprio around the MFMA pair.
__global__ void __launch_bounds__(512, 4) bconv_kernel(
    const int8_t* __restrict__ apk8, const int8_t* __restrict__ bfrag,
    const float* __restrict__ alpha, float* __restrict__ out) {
    __shared__ uint4 ldsB[4608];   // [kk36][j2][lane64], 73,728 B

    int tx = threadIdx.x;
    int lane = tx & 63, wid = tx >> 6;        // wid 0..7
    int half = lane >> 5, l31 = lane & 31;

    // bijective XCD swizzle (1568 = 8 * 196); och pairs colocate per XCD
    int bid = blockIdx.x;
    int swz = (bid & 7) * 196 + (bid >> 3);    // 0..1567
    int och = swz & 1;
    int pxb = swz >> 1;                        // 0..783
    int ocb = och * 64;

    int px = pxb * 256 + wid * 32 + l31;       // < 200704 exactly
    int n  = px / HWSZ;
    int hw = px - n * HWSZ;
    int h  = hw / WW;
    int w  = hw - h * WW;
    int ab0 = ((n * PD + h + 1) * NICQ + half) * PD + (w + 1);
    size_t ob0 = ((size_t)n * OC + ocb + half) * HWSZ + hw;

    // ---- A ring-8: issue 7 asm loads BEFORE B staging (latency overlap) ----
    v4i ar[8];
    ALOAD(0, 0); ALOAD(1, 1); ALOAD(2, 2); ALOAD(3, 3);
    ALOAD(4, 4); ALOAD(5, 5); ALOAD(6, 6);

    // ---- stage B-half via global_load_lds (direct DMA, width=16) ----
    const uint4* gB = (const uint4*)bfrag;
#pragma unroll
    for (int s = 0; s < 9; ++s) {
        int row = wid + s * 8;                 // 0..71 = kk*2 + j
        int kk = row >> 1, j = row & 1;
        const uint4* src = &gB[((kk << 2) + (och << 1) + j) * 64 + lane];
        __builtin_amdgcn_global_load_lds(
            (const uint32_t*)src,
            (uint32_t*)&ldsB[row * 64 + lane], 16, 0, 0);
    }
    __syncthreads();   // compiler drains vmcnt(0): staging DMA + our A loads

    // ---- B ring-4: preload kk = 0..2 ----
    v4i b0r[4], b1r[4];
#pragma unroll
    for (int i = 0; i < 3; ++i) {
        b0r[i] = *(const v4i*)&ldsB[i * 128 + lane];
        b1r[i] = *(const v4i*)&ldsB[i * 128 + 64 + lane];
    }

    v16i acc0 = {}, acc1 = {};
#pragma unroll
    for (int kk = 0; kk < 36; ++kk) {
        // counted wait: ensure load idx kk landed; keep up to 6 newer in flight
        if (kk <= 29)      asm volatile("s_waitcnt vmcnt(6)");
        else if (kk == 30) asm volatile("s_waitcnt vmcnt(5)");
        else if (kk == 31) asm volatile("s_waitcnt vmcnt(4)");
        else if (kk == 32) asm volatile("s_waitcnt vmcnt(3)");
        else if (kk == 33) asm volatile("s_waitcnt vmcnt(2)");
        else if (kk == 34) asm volatile("s_waitcnt vmcnt(1)");
        else               asm volatile("s_waitcnt vmcnt(0)");
        __builtin_amdgcn_sched_barrier(0);   // rule #18: no MFMA above the wait

        if (kk + 7 < 36) ALOAD((kk + 7) & 7, kk + 7);   // issue 7 ahead

        if (kk + 3 < 36) {                   // B prefetch, 3 ahead (compiler lgkmcnt)
            b0r[(kk + 3) & 3] = *(const v4i*)&ldsB[(kk + 3) * 128 + lane];
            b1r[(kk + 3) & 3] = *(const v4i*)&ldsB[(kk + 3) * 128 + 64 + lane];
        }
        v4i A = ar[kk & 7];
        __builtin_amdgcn_s_setprio(1);       // T5: favor MFMA-issuing wave
        acc0 = __builtin_amdgcn_mfma_i32_32x32x32_i8(A, b0r[kk & 3], acc0, 0, 0, 0);
        acc1 = __builtin_amdgcn_mfma_i32_32x32x32_i8(A, b1r[kk & 3], acc1, 0, 0, 0);
        __builtin_amdgcn_s_setprio(0);
    }

    __syncthreads();   // ldsB free -> reuse as transpose scratch

    // ---- epilogue: alpha-scale + wave-private LDS transpose (validated) ----
    float* tlw = (float*)ldsB + wid * (32 * 33);   // 8 waves x 4224 B
    float alf0 = alpha[ocb + l31];
    float alf1 = alpha[ocb + 32 + l31];

#pragma unroll
    for (int tn = 0; tn < 2; ++tn) {
        const v16i* ac = tn ? &acc1 : &acc0;
        float alf = tn ? alf1 : alf0;
        // C layout: col(oc)=lane&31, row(px)=(r&3)+8*(r>>2)+4*half
#pragma unroll
        for (int r = 0; r < 16; ++r) {
            int row = (r & 3) + 8 * (r >> 2) + 4 * half;
            tlw[row * 33 + l31] = (float)(*ac)[r] * alf;
        }
        // wave-synchronous transpose read: lane -> (px=l31, oc=2r+half)
#pragma unroll
        for (int r = 0; r < 16; ++r) {
            float v = tlw[l31 * 33 + 2 * r + half];
            out[ob0 + (size_t)(tn * 32 + 2 * r) * HWSZ] = v;
        }
    }
}

// ===========================================================================
// ================== bitplane fallback path (verified R5) ===================
// ===========================================================================

__global__ void __launch_bounds__(256) wpack32_kernel(
    const float* __restrict__ M, const float* __restrict__ Z,
    const float* __restrict__ rv, uint32_t* __restrict__ wpk32) {
    int gtid = blockIdx.x * blockDim.x + threadIdx.x;
    int lane = gtid & 63;
    int wid  = gtid >> 6;
    int oc   = wid / 18;
    int r    = wid - oc * 18;
    int tap  = r >> 1;
    int word = r & 1;
    int ic   = word * 64 + lane;
    int idx  = (oc * IC + ic) * NTAP + tap;

    float m  = M[idx];
    float z0 = Z[0 * NWEL + idx];
    float z1 = Z[1 * NWEL + idx];
    float z2 = Z[2 * NWEL + idx];
    float z3 = Z[3 * NWEL + idx];
    float z4 = Z[4 * NWEL + idx];
    float s  = z0 * z0 + z1 * z1 + z2 * z2 + z3 * z3 + z4 * z4;
    float A  = m * m + s * (1.0f / SCALE_F);
    float inv = 1.0f / sqrtf(A);
    float w = rv[0] * (z0 * inv);
    w += rv[1] * (z1 * inv);
    w += rv[2] * (z2 * inv);
    w += rv[3] * (z3 * inv);
    w += rv[4] * (z4 * inv);
    w += m * inv;

    unsigned long long b = __ballot(w > 0.0f);
    if (lane == 0) {
        uint64_t* wpk = (uint64_t*)wpk32;
        wpk[(oc * NTAP + tap) * 2 + word] = b;
    }
}

__global__ void __launch_bounds__(256) apack32_kernel(
    const float* __restrict__ x, uint32_t* __restrict__ apk32) {
    int q  = blockIdx.x * blockDim.x + threadIdx.x;
    int wd = blockIdx.y;
    int n  = q / HWSZ;
    int hw = q - n * HWSZ;
    int h  = hw / WW;
    int w  = hw - h * WW;
    const float* xp = x + (size_t)n * IC * HWSZ + (size_t)wd * 32 * HWSZ + hw;

    uint32_t b = 0;
#pragma unroll
    for (int c = 0; c < 32; ++c)
        b |= (uint32_t)(xp[(size_t)c * HWSZ] > 0.0f) << c;

    apk32[(size_t)wd * PLSTRIDE + (size_t)n * PLANE + (size_t)(h + 1) * PW + (w + 1)] = b;
}

__global__ void __launch_bounds__(256, 8) bconv32_kernel(
    const uint32_t* __restrict__ apk32, const uint32_t* __restrict__ wpk32,
    const float* __restrict__ alpha, float* __restrict__ out) {
    __shared__ int adj[OCPB][9];
    __shared__ float alf[OCPB];

    int tx  = threadIdx.x;
    int oc0 = blockIdx.y * OCPB;

    if (tx < OCPB) alf[tx] = alpha[oc0 + tx];
    if (tx < OCPB * 9) {
        int ocl = tx / 9, cls = tx % 9;
        int rc = cls / 3, cc = cls % 3;
        int nv = ((rc == 1) ? 3 : 2) * ((cc == 1) ? 3 : 2);
        int s = 0;
#pragma unroll
        for (int t = 0; t < NTAP; ++t) {
            int i = t / 3, j = t % 3;
            bool invld = (rc == 0 && i == 0) || (rc == 2 && i == 2) ||
                         (cc == 0 && j == 0) || (cc == 2 && j == 2);
            if (invld) {
                const uint64_t* wpk = (const uint64_t*)wpk32;
                uint64_t lo = wpk[(oc0 + ocl) * NTAP * 2 + t * 2 + 0];
                uint64_t hi = wpk[(oc0 + ocl) * NTAP * 2 + t * 2 + 1];
                s += __popcll(lo) + __popcll(hi);
            }
        }
        adj[ocl][cls] = 128 * nv + 2 * s;
    }
    __syncthreads();

    int t  = blockIdx.x * blockDim.x + tx;
    int sw = t % 14;
    int h  = (t / 14) % HH;
    int n  = t / (14 * HH);
    int w0 = sw * WPT;

    const uint32_t* ap = apk32 + (size_t)n * PLANE + (size_t)h * PW + w0;
    const uint64_t* wpk = (const uint64_t*)wpk32;

    int cnt[WPT * OCPB] = {0};
#pragma unroll 1
    for (int r = 0; r < 3; ++r) {
#pragma unroll 1
        for (int wd = 0; wd < 4; ++wd) {
            const uint32_t* p = ap + (size_t)wd * PLSTRIDE + (size_t)r * PW;
            uint32_t T[6];
#pragma unroll
            for (int c = 0; c < 6; ++c) T[c] = p[c];
#pragma unroll
            for (int j = 0; j < 3; ++j) {
#pragma unroll
                for (int ocl = 0; ocl < OCPB; ++ocl) {
                    uint64_t w2 = wpk[(oc0 + ocl) * NTAP * 2 + (r * 3 + j) * 2 + (wd >> 1)];
                    uint32_t wv = (wd & 1) ? (uint32_t)(w2 >> 32) : (uint32_t)w2;
#pragma unroll
                    for (int o = 0; o < WPT; ++o)
                        cnt[o * OCPB + ocl] += __popc(T[j + o] ^ wv);
                }
            }
        }
    }

    int rcls = (h == 0) ? 0 : ((h == HH - 1) ? 6 : 3);
    int clsL = rcls + ((w0 == 0) ? 0 : 1);
    int clsI = rcls + 1;
    int clsR = rcls + ((w0 == WW - WPT) ? 2 : 1);
    float* op = out + ((size_t)n * OC + oc0) * HWSZ + h * WW + w0;
#pragma unroll
    for (int ocl = 0; ocl < OCPB; ++ocl) {
        float a = alf[ocl];
        float4 v;
        v.x = (float)(adj[ocl][clsL] - 2 * cnt[0 * OCPB + ocl]) * a;
        v.y = (float)(adj[ocl][clsI] - 2 * cnt[1 * OCPB + ocl]) * a;
        v.z = (float)(adj[ocl][clsI] - 2 * cnt[2 * OCPB + ocl]) * a;
        v.w = (float)(adj[ocl][clsR] - 2 * cnt[3 * OCPB + ocl]) * a;
        *(float4*)(op + (size_t)ocl * HWSZ) = v;
    }
}

extern "C" void kernel_launch(void* const* d_in, const int* in_sizes, int n_in,
                              void* d_out, int out_size, void* d_ws, size_t ws_size,
                              hipStream_t stream) {
    const float* x     = (const float*)d_in[0];
    const float* M     = (const float*)d_in[1];
    const float* Z     = (const float*)d_in[2];
    const float* Alpha = (const float*)d_in[3];
    const float* rv    = (const float*)d_in[4];
    float* out = (float*)d_out;

    const size_t mfma_needed = 196608 + (size_t)NB * PD * NICQ * PD * 16 + (1 << 20);

    if (ws_size >= mfma_needed) {
        int8_t* bfrag = (int8_t*)d_ws;                      // 147,456 B
        int8_t* apk8  = (int8_t*)d_ws + 196608;             // 27,557,888 B

        prep_kernel<<<1487, 448, 0, stream>>>(x, M, Z, rv, bfrag, apk8);
        bconv_kernel<<<1568, 512, 0, stream>>>(apk8, bfrag, Alpha, out);
    } else {
        // verified bitplane fallback (R5)
        uint32_t* wpk32 = (uint32_t*)d_ws;                  // 18,432 B
        uint32_t* apk32 = (uint32_t*)((char*)d_ws + 32768); // 3,563,520 B

        hipMemsetAsync(apk32, 0, (size_t)4 * PLSTRIDE * 4, stream);
        wpack32_kernel<<<NWEL / 256, 256, 0, stream>>>(M, Z, rv, wpk32);
        apack32_kernel<<<dim3((NB * HWSZ) / 256, 4), 256, 0, stream>>>(x, apk32);
        bconv32_kernel<<<dim3((NB * HH * 14) / 256, OC / OCPB), 256, 0, stream>>>(
            apk32, wpk32, Alpha, out);
    }
}